// Round 10
// baseline (89.617 us; speedup 1.0000x reference)
//
#include <hip/hip_runtime.h>
#include <math.h>

#define D 100
#define K 4
#define NREL 1000
#define NT 256
#define MAXB 64   // max items per relation; Poisson(4.1), observed max ~15

// Single fused kernel. One block per (relation r, item-half h).
// Block id swizzle: ids come in groups of 16 = 8 relations x 2 halves, so the
// (r,h0) and (r,h1) blocks are exactly 8 ids apart -> same XCD under the
// round-robin dispatch heuristic -> W[r] is read from HBM once, the partner
// block hits L2.
// Each block deterministically re-discovers its item list in sorted-b order
// (count + block-wide exclusive scan; identical in both halves, no atomics)
// so per-item arithmetic order is fixed -> bitwise deterministic output.
__global__ __launch_bounds__(NT) void ntn_all(
    const int* __restrict__ heads, const int* __restrict__ tails,
    const int* __restrict__ rels,
    const float* __restrict__ E, const float* __restrict__ W,
    const float* __restrict__ V, const float* __restrict__ Bp,
    const float* __restrict__ U, float* __restrict__ out, int B)
{
    const int id = blockIdx.x;
    const int r  = (id >> 4) * 8 + (id & 7);   // 125 groups x 8 relations
    const int h  = (id >> 3) & 1;              // item half

    const int tid  = threadIdx.x;
    const int lane = tid & 63;
    const int w    = tid >> 6;        // wave id == tensor slice k
    const int dsub = lane / 25;       // 0/1 for lanes < 50 (e1/e2 row select)
    const int c    = lane % 25;       // float4 column group
    const bool active = (lane < 50);

    __shared__ int   lst[MAXB];
    __shared__ int   wtot[4];
    __shared__ float e12[4][2 * D];
    __shared__ float red[4][4];

    // ---- deterministic item discovery (sorted-b), identical in both halves
    const int per = (B + NT - 1) / NT;         // 16 for B=4096
    const int b0  = tid * per;
    int myc = 0;
    for (int j = 0; j < per; ++j) {
        const int b = b0 + j;
        if (b < B && rels[b] == r) ++myc;
    }
    int scan = myc;                            // inclusive scan within wave
    #pragma unroll
    for (int off = 1; off < 64; off <<= 1) {
        const int t = __shfl_up(scan, off, 64);
        if (lane >= off) scan += t;
    }
    if (lane == 63) wtot[w] = scan;
    __syncthreads();
    int woff = 0;
    #pragma unroll
    for (int ww = 0; ww < 4; ++ww) if (ww < w) woff += wtot[ww];
    const int n_all = wtot[0] + wtot[1] + wtot[2] + wtot[3];
    const int n = min(n_all, MAXB);
    if (n <= h * 4) return;                    // h=1 block idle when n<=4 (58%)
    int pos = woff + (scan - myc);             // exclusive prefix
    for (int j = 0; j < per; ++j) {
        const int b = b0 + j;
        if (b < B && rels[b] == r) { if (pos < MAXB) lst[pos] = b; ++pos; }
    }

    const float4* Wk4 = reinterpret_cast<const float4*>(W + ((size_t)r * K + w) * D * D);
    const float*  Vk  = V + ((size_t)r * K + w) * 2 * D;
    const float4* E4  = reinterpret_cast<const float4*>(E);

    // chunks: this half handles items [h*4, h*4+4), [h*4+8, h*4+12), ...
    for (int base = h * 4; base < n; base += 8) {
        const int m = min(4, n - base);
        __syncthreads();   // lst ready / previous chunk fully consumed
        // wave w gathers item base+w: head -> e12[w][0:100), tail -> [100:200)
        if (active && w < m) {
            const int b   = lst[base + w];               // wave-uniform LDS read
            const int ent = dsub ? tails[b] : heads[b];
            *(float4*)&e12[w][dsub * D + c * 4] = E4[(size_t)ent * 25 + c];
        }
        __syncthreads();

        // e2 column-group of the (up to) 4 items -> registers
        const float4 e20 = *(const float4*)&e12[0][D + c * 4];
        const float4 e21 = *(const float4*)&e12[1][D + c * 4];
        const float4 e22 = *(const float4*)&e12[2][D + c * 4];
        const float4 e23 = *(const float4*)&e12[3][D + c * 4];

        float acc0 = 0.f, acc1 = 0.f, acc2 = 0.f, acc3 = 0.f;
        if (active) {
            #pragma unroll 4   // simple loop: no hand pipeline (R6-R8 lesson)
            for (int rr = 0; rr < 50; ++rr) {
                const int d = rr * 2 + dsub;
                const float4 wv = Wk4[d * 25 + c];
                acc0 += (wv.x * e20.x + wv.y * e20.y + wv.z * e20.z + wv.w * e20.w) * e12[0][d];
                acc1 += (wv.x * e21.x + wv.y * e21.y + wv.z * e21.z + wv.w * e21.w) * e12[1][d];
                acc2 += (wv.x * e22.x + wv.y * e22.y + wv.z * e22.z + wv.w * e22.w) * e12[2][d];
                acc3 += (wv.x * e23.x + wv.y * e23.y + wv.z * e23.z + wv.w * e23.w) * e12[3][d];
            }
        }
        // g_a: v[r,k,:].[e1;e2] (all 64 lanes)
        for (int j = lane; j < 2 * D; j += 64) {
            const float vv = Vk[j];
            acc0 += vv * e12[0][j];
            acc1 += vv * e12[1][j];
            acc2 += vv * e12[2][j];
            acc3 += vv * e12[3][j];
        }
        #pragma unroll
        for (int off = 32; off > 0; off >>= 1) {
            acc0 += __shfl_down(acc0, off, 64);
            acc1 += __shfl_down(acc1, off, 64);
            acc2 += __shfl_down(acc2, off, 64);
            acc3 += __shfl_down(acc3, off, 64);
        }
        if (lane == 0) {
            red[w][0] = acc0; red[w][1] = acc1;
            red[w][2] = acc2; red[w][3] = acc3;
        }
        __syncthreads();
        if (tid < m) {   // fused epilogue (partials are block-local)
            const int rb = r * K;
            float score = 0.f;
            #pragma unroll
            for (int kk = 0; kk < K; ++kk) {
                const float gv = red[kk][tid] + Bp[rb + kk];
                score += U[rb + kk] * tanhf(gv);
            }
            out[lst[base + tid]] = 1.f / (1.f + expf(-score));
        }
    }
}

extern "C" void kernel_launch(void* const* d_in, const int* in_sizes, int n_in,
                              void* d_out, int out_size, void* d_ws, size_t ws_size,
                              hipStream_t stream) {
    const int*   heads = (const int*)d_in[0];
    const int*   tails = (const int*)d_in[1];
    const int*   rels  = (const int*)d_in[2];
    const float* E     = (const float*)d_in[3];
    const float* W     = (const float*)d_in[4];
    const float* V     = (const float*)d_in[5];
    const float* Bp    = (const float*)d_in[6];
    const float* U     = (const float*)d_in[7];
    float* out = (float*)d_out;

    const int B = in_sizes[0];
    const int nblk = ((NREL + 7) / 8) * 16;    // 2000: (r,h) pairs, swizzled
    ntn_all<<<nblk, NT, 0, stream>>>(heads, tails, rels, E, W, V, Bp, U, out, B);
}